// Round 18
// baseline (172.506 us; speedup 1.0000x reference)
//
#include <hip/hip_runtime.h>

#define NN 50000
#define NPAD 50176   // 49*1024
#define MPAD 50176   // 196*256 (GEMM row tiles)
#define NE 800000
#define BN_EPS 1e-5f

#define NSEG 782     // edge chunks of 1024
#define NBKT 49      // dst buckets of 1024 nodes

typedef __attribute__((ext_vector_type(8))) short bf16x8;
typedef __attribute__((ext_vector_type(4))) float f32x4;

__device__ __forceinline__ void atomAddF(float* p, float v) { unsafeAtomicAdd(p, v); }

__device__ __forceinline__ float bf2f(ushort u) {
    union { uint i; float f; } v; v.i = ((uint)u) << 16; return v.f;
}
__device__ __forceinline__ ushort f2bf(float f) {
    union { uint i; float f; } v; v.f = f;
    uint u = v.i;
    return (ushort)((u + 0x7FFFu + ((u >> 16) & 1u)) >> 16);  // RNE
}

// ---- fused: partition-sort (blocks 0..781) + bf16 prep (blocks 782..4418) + bnsums zero ----
__global__ __launch_bounds__(256) void k_pp(const int* __restrict__ ei,
                                            int2* __restrict__ seg,
                                            int* __restrict__ cnt2,
                                            int* __restrict__ boff2,
                                            const float* __restrict__ x, ushort* __restrict__ xb,
                                            const float* __restrict__ W1l, const float* __restrict__ W1r,
                                            const float* __restrict__ W2l, const float* __restrict__ W2r,
                                            ushort* __restrict__ Wt1, ushort* __restrict__ Wt2,
                                            float* __restrict__ bnsums) {
    const int t = threadIdx.x;
    if (blockIdx.x < NSEG) {
        __shared__ int lcnt[NBKT];
        __shared__ int lboff[NBKT];
        __shared__ int2 lbuf[1024];
        const int b = blockIdx.x;
        if (b == 0 && t < 128) reinterpret_cast<int4*>(bnsums)[t] = make_int4(0, 0, 0, 0);
        if (t < NBKT) lcnt[t] = 0;
        __syncthreads();
        int src[4], dst[4], rk[4], bkt[4];
        const int e0 = b * 1024;
        #pragma unroll
        for (int j = 0; j < 4; ++j) {
            int e = e0 + t + j * 256;
            if (e < NE) {
                src[j] = ei[e];
                dst[j] = ei[NE + e];
                bkt[j] = dst[j] >> 10;
                rk[j] = atomicAdd(&lcnt[bkt[j]], 1);
            } else rk[j] = -1;
        }
        __syncthreads();
        if (t < 64) {
            int v = (t < NBKT) ? lcnt[t] : 0;
            int y = v;
            #pragma unroll
            for (int off = 1; off < 64; off <<= 1) {
                int z = __shfl_up(y, off);
                if (t >= off) y += z;
            }
            if (t < NBKT) lboff[t] = y - v;
        }
        __syncthreads();
        #pragma unroll
        for (int j = 0; j < 4; ++j)
            if (rk[j] >= 0) lbuf[lboff[bkt[j]] + rk[j]] = make_int2(src[j], dst[j]);
        __syncthreads();
        const int total = lboff[NBKT - 1] + lcnt[NBKT - 1];
        for (int i = t; i < total; i += 256) seg[e0 + i] = lbuf[i];
        if (t < NBKT) { cnt2[b * NBKT + t] = lcnt[t]; boff2[b * NBKT + t] = lboff[t]; }
    } else {
        const int pb = blockIdx.x - NSEG;
        if (pb < 3125) {
            unsigned g = pb * 256u + t;  // < 800000 exactly
            const float4* p = reinterpret_cast<const float4*>(x) + (size_t)g * 2;
            float4 a = p[0], b2 = p[1];
            uint4 w;
            w.x = (uint)f2bf(a.x) | ((uint)f2bf(a.y) << 16);
            w.y = (uint)f2bf(a.z) | ((uint)f2bf(a.w) << 16);
            w.z = (uint)f2bf(b2.x) | ((uint)f2bf(b2.y) << 16);
            w.w = (uint)f2bf(b2.z) | ((uint)f2bf(b2.w) << 16);
            *reinterpret_cast<uint4*>(&xb[(size_t)g * 8]) = w;
        } else {
            int g = (pb - 3125) * 256 + t;  // < 131072 exactly
            if (g < 65536) {
                int n = g >> 8, k = g & 255;
                float v = (k < 128) ? W1l[k * 256 + n] : W1r[(k - 128) * 256 + n];
                Wt1[n * 256 + k] = f2bf(v);
            } else {
                int g2 = g - 65536;
                int n = g2 >> 8, k = g2 & 255;
                float v = (n < 128) ? W2l[k * 128 + n] : W2r[k * 128 + (n - 128)];
                Wt2[n * 256 + k] = f2bf(v);
            }
        }
    }
}

// ---- degree histogram + block scan: locpre (bucket-local exclusive) + bsum ----
__global__ __launch_bounds__(1024) void k_cntA(const int2* __restrict__ seg,
                                               const int* __restrict__ cnt2,
                                               const int* __restrict__ boff2,
                                               int* __restrict__ locpre,
                                               int* __restrict__ bsum) {
    __shared__ int lrk[1024];
    __shared__ int sm[1024];
    const int k = blockIdx.x, t = threadIdx.x;
    lrk[t] = 0;
    __syncthreads();
    const int node0 = k << 10;
    const int g = t >> 3, l = t & 7;
    for (int b = g; b < NSEG; b += 128) {
        const int n = cnt2[b * NBKT + k];
        const int base = b * 1024 + boff2[b * NBKT + k];
        for (int i = l; i < n; i += 8)
            atomicAdd(&lrk[seg[base + i].y - node0], 1);
    }
    __syncthreads();
    int v = lrk[t];
    sm[t] = v;
    __syncthreads();
    for (int off = 1; off < 1024; off <<= 1) {
        int y = (t >= off) ? sm[t - off] : 0;
        __syncthreads();
        sm[t] += y;
        __syncthreads();
    }
    locpre[node0 + t] = sm[t] - v;
    if (t == 1023) bsum[k] = sm[1023];
}

// ---- rowptr/invc emit + ranked fill ----
__global__ __launch_bounds__(1024) void k_rankC(const int2* __restrict__ seg,
                                                const int* __restrict__ cnt2,
                                                const int* __restrict__ boff2,
                                                const int* __restrict__ locpre,
                                                const int* __restrict__ bsum,
                                                int* __restrict__ rowptr,
                                                float* __restrict__ invc,
                                                int* __restrict__ csr_src) {
    __shared__ int lbase[1024];
    __shared__ int lrk[1024];
    __shared__ int soff_sh, stot_sh;
    const int k = blockIdx.x, t = threadIdx.x;
    if (t < 64) {
        int v = (t < k) ? bsum[t] : 0;
        #pragma unroll
        for (int off = 1; off < 64; off <<= 1) v += __shfl_xor(v, off);
        if (t == 0) { soff_sh = v; stot_sh = bsum[k]; }
    }
    lrk[t] = 0;
    __syncthreads();
    const int soff = soff_sh, stot = stot_sh;
    const int node0 = k << 10;
    const int base = locpre[node0 + t] + soff;
    lbase[t] = base;
    __syncthreads();
    const int node = node0 + t;
    if (node <= NN) {
        rowptr[node] = base;
        if (node < NN) {
            int nextb = (t < 1023) ? lbase[t + 1] : soff + stot;
            invc[node] = 1.0f / fmaxf((float)(nextb - base), 1.0f);
        }
    }
    const int g = t >> 3, l = t & 7;
    for (int b = g; b < NSEG; b += 128) {
        const int n = cnt2[b * NBKT + k];
        const int sb = b * 1024 + boff2[b * NBKT + k];
        for (int i = l; i < n; i += 8) {
            int2 e = seg[sb + i];
            int li = e.y - node0;
            int rank = atomicAdd(&lrk[li], 1);
            csr_src[lbase[li] + rank] = e.x;
        }
    }
}

// ---- gather-aggregate over 128-ch bf16 rows, 4-way edge-parallel, 4x unrolled ----
template <bool FINAL>
__global__ __launch_bounds__(256) void k_agg128(const ushort* __restrict__ feat,
                                                const int* __restrict__ rowptr,
                                                const int* __restrict__ csr_src,
                                                const float* __restrict__ invc,
                                                const float* __restrict__ z,
                                                const float* __restrict__ bias,
                                                ushort* __restrict__ aggb,
                                                float* __restrict__ outf) {
    int gw = (blockIdx.x * 256 + threadIdx.x) >> 6;
    int lane = threadIdx.x & 63;
    if (gw >= NN) return;
    const int grp = lane >> 4, sl = lane & 15;
    const int beg = rowptr[gw], end = rowptr[gw + 1];
    float acc[8] = {};
    int e = beg + grp;
    for (; e + 12 < end; e += 16) {
        int s0 = csr_src[e];
        int s1 = csr_src[e + 4];
        int s2 = csr_src[e + 8];
        int s3 = csr_src[e + 12];
        uint4 u0 = *reinterpret_cast<const uint4*>(&feat[(size_t)s0 * 128 + sl * 8]);
        uint4 u1 = *reinterpret_cast<const uint4*>(&feat[(size_t)s1 * 128 + sl * 8]);
        uint4 u2 = *reinterpret_cast<const uint4*>(&feat[(size_t)s2 * 128 + sl * 8]);
        uint4 u3 = *reinterpret_cast<const uint4*>(&feat[(size_t)s3 * 128 + sl * 8]);
        acc[0] += bf2f((ushort)u0.x) + bf2f((ushort)u1.x) + bf2f((ushort)u2.x) + bf2f((ushort)u3.x);
        acc[1] += bf2f((ushort)(u0.x >> 16)) + bf2f((ushort)(u1.x >> 16)) + bf2f((ushort)(u2.x >> 16)) + bf2f((ushort)(u3.x >> 16));
        acc[2] += bf2f((ushort)u0.y) + bf2f((ushort)u1.y) + bf2f((ushort)u2.y) + bf2f((ushort)u3.y);
        acc[3] += bf2f((ushort)(u0.y >> 16)) + bf2f((ushort)(u1.y >> 16)) + bf2f((ushort)(u2.y >> 16)) + bf2f((ushort)(u3.y >> 16));
        acc[4] += bf2f((ushort)u0.z) + bf2f((ushort)u1.z) + bf2f((ushort)u2.z) + bf2f((ushort)u3.z);
        acc[5] += bf2f((ushort)(u0.z >> 16)) + bf2f((ushort)(u1.z >> 16)) + bf2f((ushort)(u2.z >> 16)) + bf2f((ushort)(u3.z >> 16));
        acc[6] += bf2f((ushort)u0.w) + bf2f((ushort)u1.w) + bf2f((ushort)u2.w) + bf2f((ushort)u3.w);
        acc[7] += bf2f((ushort)(u0.w >> 16)) + bf2f((ushort)(u1.w >> 16)) + bf2f((ushort)(u2.w >> 16)) + bf2f((ushort)(u3.w >> 16));
    }
    for (; e < end; e += 4) {
        int s0 = csr_src[e];
        uint4 u0 = *reinterpret_cast<const uint4*>(&feat[(size_t)s0 * 128 + sl * 8]);
        acc[0] += bf2f((ushort)u0.x); acc[1] += bf2f((ushort)(u0.x >> 16));
        acc[2] += bf2f((ushort)u0.y); acc[3] += bf2f((ushort)(u0.y >> 16));
        acc[4] += bf2f((ushort)u0.z); acc[5] += bf2f((ushort)(u0.z >> 16));
        acc[6] += bf2f((ushort)u0.w); acc[7] += bf2f((ushort)(u0.w >> 16));
    }
    #pragma unroll
    for (int i = 0; i < 8; ++i) {
        acc[i] += __shfl_xor(acc[i], 16);
        acc[i] += __shfl_xor(acc[i], 32);
    }
    if (grp == 0) {
        const float ic = invc[gw];
        if constexpr (FINAL) {
            const float* zp = &z[(size_t)gw * 128 + sl * 8];
            float4 z0 = *reinterpret_cast<const float4*>(zp);
            float4 z1 = *reinterpret_cast<const float4*>(zp + 4);
            float4 b0 = *reinterpret_cast<const float4*>(&bias[sl * 8]);
            float4 b1 = *reinterpret_cast<const float4*>(&bias[sl * 8 + 4]);
            float4 o0, o1;
            o0.x = fmaf(acc[0], ic, z0.x + b0.x);
            o0.y = fmaf(acc[1], ic, z0.y + b0.y);
            o0.z = fmaf(acc[2], ic, z0.z + b0.z);
            o0.w = fmaf(acc[3], ic, z0.w + b0.w);
            o1.x = fmaf(acc[4], ic, z1.x + b1.x);
            o1.y = fmaf(acc[5], ic, z1.y + b1.y);
            o1.z = fmaf(acc[6], ic, z1.z + b1.z);
            o1.w = fmaf(acc[7], ic, z1.w + b1.w);
            float* op = &outf[(size_t)gw * 128 + sl * 8];
            *reinterpret_cast<float4*>(op) = o0;
            *reinterpret_cast<float4*>(op + 4) = o1;
        } else {
            uint4 o;
            o.x = (uint)f2bf(acc[0] * ic) | ((uint)f2bf(acc[1] * ic) << 16);
            o.y = (uint)f2bf(acc[2] * ic) | ((uint)f2bf(acc[3] * ic) << 16);
            o.z = (uint)f2bf(acc[4] * ic) | ((uint)f2bf(acc[5] * ic) << 16);
            o.w = (uint)f2bf(acc[6] * ic) | ((uint)f2bf(acc[7] * ic) << 16);
            *reinterpret_cast<uint4*>(&aggb[(size_t)gw * 128 + sl * 8]) = o;
        }
    }
}

// ---- MFMA GEMM: out = [A1 | A2] @ Wt^T (+bias) ----
// Block = 256 rows x 64 cols (wave tile 64x64, acc[4][4]); grid 784, XCD-chunked
// swizzle (Q=98 exact). B slice in LDS once (26MB total B traffic); barrier-free
// K-loop, A direct from L2. BN1: fused bnfin from bnsums+gamma+beta.
template <int K1, int K2, int NC, bool STATS, bool BN1, int OUTMODE>
__global__ __launch_bounds__(256, 3) void k_mm(const ushort* __restrict__ A1,
                                               const ushort* __restrict__ A2,
                                               const ushort* __restrict__ Wt,
                                               const float* __restrict__ bias,
                                               const float* __restrict__ gamma,
                                               const float* __restrict__ beta,
                                               float* __restrict__ bnsums,
                                               ushort* __restrict__ outb,
                                               float* __restrict__ outf) {
    constexpr int KT = K1 + K2;
    constexpr int NIT = KT / 32;
    constexpr int BSTR = 264;            // LDS col stride (ushorts)
    constexpr int NWG = 784, Q = NWG / 8;   // 98, R=0
    __shared__ ushort Bs[64 * BSTR];
    __shared__ float sred[4][4][16][2];
    __shared__ float scs[256], shs[256];
    const int t = threadIdx.x;
    const int lane = t & 63, wid = t >> 6;
    const int bid = blockIdx.x;
    const int xcd = bid & 7, idx = bid >> 3;
    const int logical = xcd * Q + idx;
    const int r0 = (logical >> 2) * 256, c0 = (logical & 3) * 64;
    const int lr = lane & 15, lg = lane >> 4;
    const int wrow = r0 + wid * 64;

    if constexpr (BN1) {
        float mu = bnsums[t & 255] * (1.0f / NN);
        float var = bnsums[256 + (t & 255)] * (1.0f / NN) - mu * mu;
        float s = gamma[t & 255] * rsqrtf(var + BN_EPS);
        scs[t & 255] = s;
        shs[t & 255] = beta[t & 255] - mu * s;
    }
    // B preload: 64 cols x KT k; coalesced
    #pragma unroll
    for (int i = 0; i < 64 * KT / 8 / 256; ++i) {
        int idx2 = i * 256 + t;
        int col = idx2 / (KT / 8);
        int slot = idx2 % (KT / 8);
        *reinterpret_cast<bf16x8*>(&Bs[col * BSTR + slot * 8]) =
            *reinterpret_cast<const bf16x8*>(&Wt[(size_t)(c0 + col) * KT + slot * 8]);
    }
    __syncthreads();

    f32x4 acc[4][4] = {};
    #pragma unroll
    for (int it = 0; it < NIT; ++it) {
        const int kt = it * 32;
        const ushort* __restrict__ Ap = (kt < K1) ? A1 : A2;
        const int AK = (kt < K1) ? K1 : K2;
        const int ak = (kt < K1) ? kt : kt - K1;
        bf16x8 af[4];
        #pragma unroll
        for (int mi = 0; mi < 4; ++mi) {
            af[mi] = *reinterpret_cast<const bf16x8*>(
                &Ap[(size_t)(wrow + mi * 16 + lr) * AK + ak + lg * 8]);
            if constexpr (BN1) {   // only used with K2==0 (ak == kt)
                const int cb = kt + lg * 8;
                #pragma unroll
                for (int j = 0; j < 8; ++j) {
                    float f = bf2f((ushort)af[mi][j]);
                    f = fmaxf(fmaf(f, scs[cb + j], shs[cb + j]), 0.f);
                    af[mi][j] = (short)f2bf(f);
                }
            }
        }
        bf16x8 bf[4];
        #pragma unroll
        for (int nj = 0; nj < 4; ++nj)
            bf[nj] = *reinterpret_cast<bf16x8*>(&Bs[(nj * 16 + lr) * BSTR + kt + lg * 8]);
        #pragma unroll
        for (int mi = 0; mi < 4; ++mi)
            #pragma unroll
            for (int nj = 0; nj < 4; ++nj)
                acc[mi][nj] = __builtin_amdgcn_mfma_f32_16x16x32_bf16(af[mi], bf[nj], acc[mi][nj], 0, 0, 0);
    }

    float ssum[4] = {}, s2sum[4] = {};
    #pragma unroll
    for (int nj = 0; nj < 4; ++nj) {
        const int col = c0 + nj * 16 + lr;
        float bv = 0.f;
        if constexpr (OUTMODE == 0) bv = bias[col];
        #pragma unroll
        for (int mi = 0; mi < 4; ++mi) {
            const int rbase = wrow + mi * 16;
            if (rbase + 16 > NN) continue;
            #pragma unroll
            for (int reg = 0; reg < 4; ++reg) {
                const int row = rbase + lg * 4 + reg;
                float d = acc[mi][nj][reg] + bv;
                if constexpr (STATS) { ssum[nj] += d; s2sum[nj] += d * d; }
                if constexpr (OUTMODE == 0) {
                    outb[(size_t)row * NC + col] = f2bf(d);
                } else {
                    if (col < 128) outb[(size_t)row * 128 + col] = f2bf(d);
                    else outf[(size_t)row * 128 + (col - 128)] = d;
                }
            }
        }
    }
    if constexpr (STATS) {
        #pragma unroll
        for (int nj = 0; nj < 4; ++nj) {
            ssum[nj] += __shfl_xor(ssum[nj], 16); ssum[nj] += __shfl_xor(ssum[nj], 32);
            s2sum[nj] += __shfl_xor(s2sum[nj], 16); s2sum[nj] += __shfl_xor(s2sum[nj], 32);
        }
        if (lane < 16) {
            #pragma unroll
            for (int nj = 0; nj < 4; ++nj) {
                sred[wid][nj][lane][0] = ssum[nj];
                sred[wid][nj][lane][1] = s2sum[nj];
            }
        }
        __syncthreads();
        if (wid == 0 && lane < 16) {
            #pragma unroll
            for (int nj = 0; nj < 4; ++nj) {
                const int col = c0 + nj * 16 + lane;
                float s = sred[0][nj][lane][0] + sred[1][nj][lane][0] + sred[2][nj][lane][0] + sred[3][nj][lane][0];
                float s2 = sred[0][nj][lane][1] + sred[1][nj][lane][1] + sred[2][nj][lane][1] + sred[3][nj][lane][1];
                atomAddF(&bnsums[col], s);
                atomAddF(&bnsums[256 + col], s2);
            }
        }
    }
}

extern "C" void kernel_launch(void* const* d_in, const int* in_sizes, int n_in,
                              void* d_out, int out_size, void* d_ws, size_t ws_size,
                              hipStream_t stream) {
    const float* x    = (const float*)d_in[0];
    const int*   ei   = (const int*)d_in[1];
    const float* W1l  = (const float*)d_in[2];
    const float* b1l  = (const float*)d_in[3];
    const float* W1r  = (const float*)d_in[4];
    const float* gam1 = (const float*)d_in[5];
    const float* bet1 = (const float*)d_in[6];
    const float* W2l  = (const float*)d_in[7];
    const float* b2l  = (const float*)d_in[8];
    const float* W2r  = (const float*)d_in[9];
    float* out = (float*)d_out;

    char* p = (char*)d_ws;
    ushort* xb   = (ushort*)p; p += (size_t)MPAD * 128 * 2;
    ushort* hb   = (ushort*)p; p += (size_t)MPAD * 256 * 2;
    ushort* aggb = (ushort*)p; p += (size_t)MPAD * 128 * 2;
    ushort* y2b  = (ushort*)p; p += (size_t)MPAD * 128 * 2;
    float*  zf   = (float*)p;  p += (size_t)MPAD * 128 * 4;
    ushort* Wt1  = (ushort*)p; p += 256 * 256 * 2;
    ushort* Wt2  = (ushort*)p; p += 256 * 256 * 2;
    float* bnsums = (float*)p; p += 512 * 4 + 2048;
    float* invc   = (float*)p; p += (size_t)NPAD * 4;
    int*   rowptr = (int*)p;   p += (size_t)(NPAD + 4) * 4;
    int*   csr_src= (int*)p;   p += (size_t)NE * 4;
    int2*  seg    = (int2*)p;  p += (size_t)NE * 8;
    int*   cnt2   = (int*)p;   p += (size_t)NSEG * NBKT * 4;
    int*   boff2  = (int*)p;   p += (size_t)NSEG * NBKT * 4;
    int*   bsum   = (int*)p;   p += 64 * 4;
    int*   locpre = (int*)aggb;   // overlay: consumed by k_rankC before aggb written

    // 1: partition + bf16 prep + bnsums zero
    k_pp<<<NSEG + 3637, 256, 0, stream>>>(ei, seg, cnt2, boff2,
                                          x, xb, W1l, W1r, W2l, W2r, Wt1, Wt2, bnsums);
    // 2: degree histogram + block scan
    k_cntA<<<NBKT, 1024, 0, stream>>>(seg, cnt2, boff2, locpre, bsum);
    // 3: rowptr/invc emit + ranked fill
    k_rankC<<<NBKT, 1024, 0, stream>>>(seg, cnt2, boff2, locpre, bsum, rowptr, invc, csr_src);

    // 4: Layer 1 aggregate
    k_agg128<false><<<12500, 256, 0, stream>>>(xb, rowptr, csr_src, invc, nullptr, nullptr, aggb, nullptr);
    // 5: GEMM [agg|x]@Wt1 + bias, fused BN stats
    k_mm<128, 128, 256, true, false, 0><<<784, 256, 0, stream>>>(
        aggb, xb, Wt1, b1l, nullptr, nullptr, bnsums, hb, nullptr);
    // 6: GEMM relu(bn(h))@[W2l|W2r] with fused bnfin -> y2 (bf16) + z (fp32)
    k_mm<256, 0, 256, false, true, 1><<<784, 256, 0, stream>>>(
        hb, nullptr, Wt2, nullptr, gam1, bet1, bnsums, y2b, zf);
    // 7: Layer 2 aggregate + z + bias -> out
    k_agg128<true><<<12500, 256, 0, stream>>>(y2b, rowptr, csr_src, invc, zf, b2l, nullptr, out);
}

// Round 19
// 161.012 us; speedup vs baseline: 1.0714x; 1.0714x over previous
//
#include <hip/hip_runtime.h>

#define NN 50000
#define NPAD 50176   // 49*1024
#define MPAD 50176   // row-tile padded
#define NE 800000
#define BN_EPS 1e-5f

#define NSEG 782     // edge chunks of 1024
#define NBKT 49      // dst buckets of 1024 nodes

typedef __attribute__((ext_vector_type(8))) short bf16x8;
typedef __attribute__((ext_vector_type(4))) float f32x4;

__device__ __forceinline__ void atomAddF(float* p, float v) { unsafeAtomicAdd(p, v); }

__device__ __forceinline__ float bf2f(ushort u) {
    union { uint i; float f; } v; v.i = ((uint)u) << 16; return v.f;
}
__device__ __forceinline__ ushort f2bf(float f) {
    union { uint i; float f; } v; v.f = f;
    uint u = v.i;
    return (ushort)((u + 0x7FFFu + ((u >> 16) & 1u)) >> 16);  // RNE
}

// ---- fused: partition-sort (blocks 0..781) + bf16 prep (blocks 782..4418) + bnsums zero ----
__global__ __launch_bounds__(256) void k_pp(const int* __restrict__ ei,
                                            int2* __restrict__ seg,
                                            int* __restrict__ cnt2,
                                            int* __restrict__ boff2,
                                            const float* __restrict__ x, ushort* __restrict__ xb,
                                            const float* __restrict__ W1l, const float* __restrict__ W1r,
                                            const float* __restrict__ W2l, const float* __restrict__ W2r,
                                            ushort* __restrict__ Wt1, ushort* __restrict__ Wt2,
                                            float* __restrict__ bnsums) {
    const int t = threadIdx.x;
    if (blockIdx.x < NSEG) {
        __shared__ int lcnt[NBKT];
        __shared__ int lboff[NBKT];
        __shared__ int2 lbuf[1024];
        const int b = blockIdx.x;
        if (b == 0 && t < 128) reinterpret_cast<int4*>(bnsums)[t] = make_int4(0, 0, 0, 0);
        if (t < NBKT) lcnt[t] = 0;
        __syncthreads();
        int src[4], dst[4], rk[4], bkt[4];
        const int e0 = b * 1024;
        #pragma unroll
        for (int j = 0; j < 4; ++j) {
            int e = e0 + t + j * 256;
            if (e < NE) {
                src[j] = ei[e];
                dst[j] = ei[NE + e];
                bkt[j] = dst[j] >> 10;
                rk[j] = atomicAdd(&lcnt[bkt[j]], 1);
            } else rk[j] = -1;
        }
        __syncthreads();
        if (t < 64) {
            int v = (t < NBKT) ? lcnt[t] : 0;
            int y = v;
            #pragma unroll
            for (int off = 1; off < 64; off <<= 1) {
                int z = __shfl_up(y, off);
                if (t >= off) y += z;
            }
            if (t < NBKT) lboff[t] = y - v;
        }
        __syncthreads();
        #pragma unroll
        for (int j = 0; j < 4; ++j)
            if (rk[j] >= 0) lbuf[lboff[bkt[j]] + rk[j]] = make_int2(src[j], dst[j]);
        __syncthreads();
        const int total = lboff[NBKT - 1] + lcnt[NBKT - 1];
        for (int i = t; i < total; i += 256) seg[e0 + i] = lbuf[i];
        if (t < NBKT) { cnt2[b * NBKT + t] = lcnt[t]; boff2[b * NBKT + t] = lboff[t]; }
    } else {
        const int pb = blockIdx.x - NSEG;
        if (pb < 3125) {
            unsigned g = pb * 256u + t;  // < 800000 exactly
            const float4* p = reinterpret_cast<const float4*>(x) + (size_t)g * 2;
            float4 a = p[0], b2 = p[1];
            uint4 w;
            w.x = (uint)f2bf(a.x) | ((uint)f2bf(a.y) << 16);
            w.y = (uint)f2bf(a.z) | ((uint)f2bf(a.w) << 16);
            w.z = (uint)f2bf(b2.x) | ((uint)f2bf(b2.y) << 16);
            w.w = (uint)f2bf(b2.z) | ((uint)f2bf(b2.w) << 16);
            *reinterpret_cast<uint4*>(&xb[(size_t)g * 8]) = w;
        } else {
            int g = (pb - 3125) * 256 + t;  // < 131072 exactly
            if (g < 65536) {
                int n = g >> 8, k = g & 255;
                float v = (k < 128) ? W1l[k * 256 + n] : W1r[(k - 128) * 256 + n];
                Wt1[n * 256 + k] = f2bf(v);
            } else {
                int g2 = g - 65536;
                int n = g2 >> 8, k = g2 & 255;
                float v = (n < 128) ? W2l[k * 128 + n] : W2r[k * 128 + (n - 128)];
                Wt2[n * 256 + k] = f2bf(v);
            }
        }
    }
}

// ---- degree histogram + block scan: locpre (bucket-local exclusive) + bsum ----
__global__ __launch_bounds__(1024) void k_cntA(const int2* __restrict__ seg,
                                               const int* __restrict__ cnt2,
                                               const int* __restrict__ boff2,
                                               int* __restrict__ locpre,
                                               int* __restrict__ bsum) {
    __shared__ int lrk[1024];
    __shared__ int sm[1024];
    const int k = blockIdx.x, t = threadIdx.x;
    lrk[t] = 0;
    __syncthreads();
    const int node0 = k << 10;
    const int g = t >> 3, l = t & 7;
    for (int b = g; b < NSEG; b += 128) {
        const int n = cnt2[b * NBKT + k];
        const int base = b * 1024 + boff2[b * NBKT + k];
        for (int i = l; i < n; i += 8)
            atomicAdd(&lrk[seg[base + i].y - node0], 1);
    }
    __syncthreads();
    int v = lrk[t];
    sm[t] = v;
    __syncthreads();
    for (int off = 1; off < 1024; off <<= 1) {
        int y = (t >= off) ? sm[t - off] : 0;
        __syncthreads();
        sm[t] += y;
        __syncthreads();
    }
    locpre[node0 + t] = sm[t] - v;
    if (t == 1023) bsum[k] = sm[1023];
}

// ---- rowptr/invc emit + ranked fill ----
__global__ __launch_bounds__(1024) void k_rankC(const int2* __restrict__ seg,
                                                const int* __restrict__ cnt2,
                                                const int* __restrict__ boff2,
                                                const int* __restrict__ locpre,
                                                const int* __restrict__ bsum,
                                                int* __restrict__ rowptr,
                                                float* __restrict__ invc,
                                                int* __restrict__ csr_src) {
    __shared__ int lbase[1024];
    __shared__ int lrk[1024];
    __shared__ int soff_sh, stot_sh;
    const int k = blockIdx.x, t = threadIdx.x;
    if (t < 64) {
        int v = (t < k) ? bsum[t] : 0;
        #pragma unroll
        for (int off = 1; off < 64; off <<= 1) v += __shfl_xor(v, off);
        if (t == 0) { soff_sh = v; stot_sh = bsum[k]; }
    }
    lrk[t] = 0;
    __syncthreads();
    const int soff = soff_sh, stot = stot_sh;
    const int node0 = k << 10;
    const int base = locpre[node0 + t] + soff;
    lbase[t] = base;
    __syncthreads();
    const int node = node0 + t;
    if (node <= NN) {
        rowptr[node] = base;
        if (node < NN) {
            int nextb = (t < 1023) ? lbase[t + 1] : soff + stot;
            invc[node] = 1.0f / fmaxf((float)(nextb - base), 1.0f);
        }
    }
    const int g = t >> 3, l = t & 7;
    for (int b = g; b < NSEG; b += 128) {
        const int n = cnt2[b * NBKT + k];
        const int sb = b * 1024 + boff2[b * NBKT + k];
        for (int i = l; i < n; i += 8) {
            int2 e = seg[sb + i];
            int li = e.y - node0;
            int rank = atomicAdd(&lrk[li], 1);
            csr_src[lbase[li] + rank] = e.x;
        }
    }
}

// ---- gather-aggregate over 128-ch bf16 rows, 4-way edge-parallel, 4x unrolled ----
template <bool FINAL>
__global__ __launch_bounds__(256) void k_agg128(const ushort* __restrict__ feat,
                                                const int* __restrict__ rowptr,
                                                const int* __restrict__ csr_src,
                                                const float* __restrict__ invc,
                                                const float* __restrict__ z,
                                                const float* __restrict__ bias,
                                                ushort* __restrict__ aggb,
                                                float* __restrict__ outf) {
    int gw = (blockIdx.x * 256 + threadIdx.x) >> 6;
    int lane = threadIdx.x & 63;
    if (gw >= NN) return;
    const int grp = lane >> 4, sl = lane & 15;
    const int beg = rowptr[gw], end = rowptr[gw + 1];
    float acc[8] = {};
    int e = beg + grp;
    for (; e + 12 < end; e += 16) {
        int s0 = csr_src[e];
        int s1 = csr_src[e + 4];
        int s2 = csr_src[e + 8];
        int s3 = csr_src[e + 12];
        uint4 u0 = *reinterpret_cast<const uint4*>(&feat[(size_t)s0 * 128 + sl * 8]);
        uint4 u1 = *reinterpret_cast<const uint4*>(&feat[(size_t)s1 * 128 + sl * 8]);
        uint4 u2 = *reinterpret_cast<const uint4*>(&feat[(size_t)s2 * 128 + sl * 8]);
        uint4 u3 = *reinterpret_cast<const uint4*>(&feat[(size_t)s3 * 128 + sl * 8]);
        acc[0] += bf2f((ushort)u0.x) + bf2f((ushort)u1.x) + bf2f((ushort)u2.x) + bf2f((ushort)u3.x);
        acc[1] += bf2f((ushort)(u0.x >> 16)) + bf2f((ushort)(u1.x >> 16)) + bf2f((ushort)(u2.x >> 16)) + bf2f((ushort)(u3.x >> 16));
        acc[2] += bf2f((ushort)u0.y) + bf2f((ushort)u1.y) + bf2f((ushort)u2.y) + bf2f((ushort)u3.y);
        acc[3] += bf2f((ushort)(u0.y >> 16)) + bf2f((ushort)(u1.y >> 16)) + bf2f((ushort)(u2.y >> 16)) + bf2f((ushort)(u3.y >> 16));
        acc[4] += bf2f((ushort)u0.z) + bf2f((ushort)u1.z) + bf2f((ushort)u2.z) + bf2f((ushort)u3.z);
        acc[5] += bf2f((ushort)(u0.z >> 16)) + bf2f((ushort)(u1.z >> 16)) + bf2f((ushort)(u2.z >> 16)) + bf2f((ushort)(u3.z >> 16));
        acc[6] += bf2f((ushort)u0.w) + bf2f((ushort)u1.w) + bf2f((ushort)u2.w) + bf2f((ushort)u3.w);
        acc[7] += bf2f((ushort)(u0.w >> 16)) + bf2f((ushort)(u1.w >> 16)) + bf2f((ushort)(u2.w >> 16)) + bf2f((ushort)(u3.w >> 16));
    }
    for (; e < end; e += 4) {
        int s0 = csr_src[e];
        uint4 u0 = *reinterpret_cast<const uint4*>(&feat[(size_t)s0 * 128 + sl * 8]);
        acc[0] += bf2f((ushort)u0.x); acc[1] += bf2f((ushort)(u0.x >> 16));
        acc[2] += bf2f((ushort)u0.y); acc[3] += bf2f((ushort)(u0.y >> 16));
        acc[4] += bf2f((ushort)u0.z); acc[5] += bf2f((ushort)(u0.z >> 16));
        acc[6] += bf2f((ushort)u0.w); acc[7] += bf2f((ushort)(u0.w >> 16));
    }
    #pragma unroll
    for (int i = 0; i < 8; ++i) {
        acc[i] += __shfl_xor(acc[i], 16);
        acc[i] += __shfl_xor(acc[i], 32);
    }
    if (grp == 0) {
        const float ic = invc[gw];
        if constexpr (FINAL) {
            const float* zp = &z[(size_t)gw * 128 + sl * 8];
            float4 z0 = *reinterpret_cast<const float4*>(zp);
            float4 z1 = *reinterpret_cast<const float4*>(zp + 4);
            float4 b0 = *reinterpret_cast<const float4*>(&bias[sl * 8]);
            float4 b1 = *reinterpret_cast<const float4*>(&bias[sl * 8 + 4]);
            float4 o0, o1;
            o0.x = fmaf(acc[0], ic, z0.x + b0.x);
            o0.y = fmaf(acc[1], ic, z0.y + b0.y);
            o0.z = fmaf(acc[2], ic, z0.z + b0.z);
            o0.w = fmaf(acc[3], ic, z0.w + b0.w);
            o1.x = fmaf(acc[4], ic, z1.x + b1.x);
            o1.y = fmaf(acc[5], ic, z1.y + b1.y);
            o1.z = fmaf(acc[6], ic, z1.z + b1.z);
            o1.w = fmaf(acc[7], ic, z1.w + b1.w);
            float* op = &outf[(size_t)gw * 128 + sl * 8];
            *reinterpret_cast<float4*>(op) = o0;
            *reinterpret_cast<float4*>(op + 4) = o1;
        } else {
            uint4 o;
            o.x = (uint)f2bf(acc[0] * ic) | ((uint)f2bf(acc[1] * ic) << 16);
            o.y = (uint)f2bf(acc[2] * ic) | ((uint)f2bf(acc[3] * ic) << 16);
            o.z = (uint)f2bf(acc[4] * ic) | ((uint)f2bf(acc[5] * ic) << 16);
            o.w = (uint)f2bf(acc[6] * ic) | ((uint)f2bf(acc[7] * ic) << 16);
            *reinterpret_cast<uint4*>(&aggb[(size_t)gw * 128 + sl * 8]) = o;
        }
    }
}

// ---- MFMA GEMM: out = [A1 | A2] @ Wt^T (+bias) ----
// r17 structure (best measured): 1D grid 1564 = 391 row-tiles x 4 col-tiles,
// XCD-chunked bijective swizzle; B slice (64 cols x KT) in LDS once;
// barrier-free K-loop, A fragments direct from L2. launch_bounds(256,4).
template <int K1, int K2, int NC, bool STATS, bool BN1, int OUTMODE>
__global__ __launch_bounds__(256, 4) void k_mm(const ushort* __restrict__ A1,
                                               const ushort* __restrict__ A2,
                                               const ushort* __restrict__ Wt,
                                               const float* __restrict__ bias,
                                               const float* __restrict__ gamma,
                                               const float* __restrict__ beta,
                                               float* __restrict__ bnsums,
                                               ushort* __restrict__ outb,
                                               float* __restrict__ outf) {
    constexpr int KT = K1 + K2;
    constexpr int NIT = KT / 32;
    constexpr int BSTR = 264;            // LDS col stride (ushorts)
    constexpr int NWG = 1564, Q = NWG / 8, R = NWG % 8;   // 195, 4
    __shared__ ushort Bs[64 * BSTR];
    __shared__ float sred[4][4][16][2];
    __shared__ float scs[256], shs[256];
    const int t = threadIdx.x;
    const int lane = t & 63, wid = t >> 6;
    const int bid = blockIdx.x;
    const int xcd = bid & 7, idx = bid >> 3;
    const int logical = (xcd < R ? xcd * (Q + 1) : R * (Q + 1) + (xcd - R) * Q) + idx;
    const int r0 = (logical >> 2) * 128, c0 = (logical & 3) * 64;
    const int lr = lane & 15, lg = lane >> 4;
    const int wrow = r0 + wid * 32;

    if constexpr (BN1) {   // fused bnfin: per-block compute of BN scale/shift
        float mu = bnsums[t & 255] * (1.0f / NN);
        float var = bnsums[256 + (t & 255)] * (1.0f / NN) - mu * mu;
        float s = gamma[t & 255] * rsqrtf(var + BN_EPS);
        scs[t & 255] = s;
        shs[t & 255] = beta[t & 255] - mu * s;
    }
    // B preload: 64 cols x KT k; coalesced
    #pragma unroll
    for (int i = 0; i < 64 * KT / 8 / 256; ++i) {
        int idx2 = i * 256 + t;
        int col = idx2 / (KT / 8);
        int slot = idx2 % (KT / 8);
        *reinterpret_cast<bf16x8*>(&Bs[col * BSTR + slot * 8]) =
            *reinterpret_cast<const bf16x8*>(&Wt[(size_t)(c0 + col) * KT + slot * 8]);
    }
    __syncthreads();

    f32x4 acc[2][4] = {};
    #pragma unroll
    for (int it = 0; it < NIT; ++it) {
        const int kt = it * 32;
        const ushort* __restrict__ Ap = (kt < K1) ? A1 : A2;
        const int AK = (kt < K1) ? K1 : K2;
        const int ak = (kt < K1) ? kt : kt - K1;
        bf16x8 af[2];
        #pragma unroll
        for (int mi = 0; mi < 2; ++mi) {
            af[mi] = *reinterpret_cast<const bf16x8*>(
                &Ap[(size_t)(wrow + mi * 16 + lr) * AK + ak + lg * 8]);
            if constexpr (BN1) {   // only used with K2==0 (ak == kt)
                const int cb = kt + lg * 8;
                #pragma unroll
                for (int j = 0; j < 8; ++j) {
                    float f = bf2f((ushort)af[mi][j]);
                    f = fmaxf(fmaf(f, scs[cb + j], shs[cb + j]), 0.f);
                    af[mi][j] = (short)f2bf(f);
                }
            }
        }
        bf16x8 bf[4];
        #pragma unroll
        for (int nj = 0; nj < 4; ++nj)
            bf[nj] = *reinterpret_cast<bf16x8*>(&Bs[(nj * 16 + lr) * BSTR + kt + lg * 8]);
        #pragma unroll
        for (int mi = 0; mi < 2; ++mi)
            #pragma unroll
            for (int nj = 0; nj < 4; ++nj)
                acc[mi][nj] = __builtin_amdgcn_mfma_f32_16x16x32_bf16(af[mi], bf[nj], acc[mi][nj], 0, 0, 0);
    }

    float ssum[4] = {}, s2sum[4] = {};
    #pragma unroll
    for (int nj = 0; nj < 4; ++nj) {
        const int col = c0 + nj * 16 + lr;
        float bv = 0.f;
        if constexpr (OUTMODE == 0) bv = bias[col];
        #pragma unroll
        for (int mi = 0; mi < 2; ++mi) {
            const int rbase = wrow + mi * 16;
            if (rbase + 16 > NN) continue;
            #pragma unroll
            for (int reg = 0; reg < 4; ++reg) {
                const int row = rbase + lg * 4 + reg;
                float d = acc[mi][nj][reg] + bv;
                if constexpr (STATS) { ssum[nj] += d; s2sum[nj] += d * d; }
                if constexpr (OUTMODE == 0) {
                    outb[(size_t)row * NC + col] = f2bf(d);
                } else {
                    if (col < 128) outb[(size_t)row * 128 + col] = f2bf(d);
                    else outf[(size_t)row * 128 + (col - 128)] = d;
                }
            }
        }
    }
    if constexpr (STATS) {
        #pragma unroll
        for (int nj = 0; nj < 4; ++nj) {
            ssum[nj] += __shfl_xor(ssum[nj], 16); ssum[nj] += __shfl_xor(ssum[nj], 32);
            s2sum[nj] += __shfl_xor(s2sum[nj], 16); s2sum[nj] += __shfl_xor(s2sum[nj], 32);
        }
        if (lane < 16) {
            #pragma unroll
            for (int nj = 0; nj < 4; ++nj) {
                sred[wid][nj][lane][0] = ssum[nj];
                sred[wid][nj][lane][1] = s2sum[nj];
            }
        }
        __syncthreads();
        if (wid == 0 && lane < 16) {
            #pragma unroll
            for (int nj = 0; nj < 4; ++nj) {
                const int col = c0 + nj * 16 + lane;
                float s = sred[0][nj][lane][0] + sred[1][nj][lane][0] + sred[2][nj][lane][0] + sred[3][nj][lane][0];
                float s2 = sred[0][nj][lane][1] + sred[1][nj][lane][1] + sred[2][nj][lane][1] + sred[3][nj][lane][1];
                atomAddF(&bnsums[col], s);
                atomAddF(&bnsums[256 + col], s2);
            }
        }
    }
}

extern "C" void kernel_launch(void* const* d_in, const int* in_sizes, int n_in,
                              void* d_out, int out_size, void* d_ws, size_t ws_size,
                              hipStream_t stream) {
    const float* x    = (const float*)d_in[0];
    const int*   ei   = (const int*)d_in[1];
    const float* W1l  = (const float*)d_in[2];
    const float* b1l  = (const float*)d_in[3];
    const float* W1r  = (const float*)d_in[4];
    const float* gam1 = (const float*)d_in[5];
    const float* bet1 = (const float*)d_in[6];
    const float* W2l  = (const float*)d_in[7];
    const float* b2l  = (const float*)d_in[8];
    const float* W2r  = (const float*)d_in[9];
    float* out = (float*)d_out;

    char* p = (char*)d_ws;
    ushort* xb   = (ushort*)p; p += (size_t)MPAD * 128 * 2;
    ushort* hb   = (ushort*)p; p += (size_t)MPAD * 256 * 2;
    ushort* aggb = (ushort*)p; p += (size_t)MPAD * 128 * 2;
    ushort* y2b  = (ushort*)p; p += (size_t)MPAD * 128 * 2;
    float*  zf   = (float*)p;  p += (size_t)MPAD * 128 * 4;
    ushort* Wt1  = (ushort*)p; p += 256 * 256 * 2;
    ushort* Wt2  = (ushort*)p; p += 256 * 256 * 2;
    float* bnsums = (float*)p; p += 512 * 4 + 2048;
    float* invc   = (float*)p; p += (size_t)NPAD * 4;
    int*   rowptr = (int*)p;   p += (size_t)(NPAD + 4) * 4;
    int*   csr_src= (int*)p;   p += (size_t)NE * 4;
    int2*  seg    = (int2*)p;  p += (size_t)NE * 8;
    int*   cnt2   = (int*)p;   p += (size_t)NSEG * NBKT * 4;
    int*   boff2  = (int*)p;   p += (size_t)NSEG * NBKT * 4;
    int*   bsum   = (int*)p;   p += 64 * 4;
    int*   locpre = (int*)aggb;   // overlay: consumed by k_rankC before aggb written

    // 1: partition + bf16 prep + bnsums zero
    k_pp<<<NSEG + 3637, 256, 0, stream>>>(ei, seg, cnt2, boff2,
                                          x, xb, W1l, W1r, W2l, W2r, Wt1, Wt2, bnsums);
    // 2: degree histogram + block scan
    k_cntA<<<NBKT, 1024, 0, stream>>>(seg, cnt2, boff2, locpre, bsum);
    // 3: rowptr/invc emit + ranked fill
    k_rankC<<<NBKT, 1024, 0, stream>>>(seg, cnt2, boff2, locpre, bsum, rowptr, invc, csr_src);

    // 4: Layer 1 aggregate
    k_agg128<false><<<12500, 256, 0, stream>>>(xb, rowptr, csr_src, invc, nullptr, nullptr, aggb, nullptr);
    // 5: GEMM [agg|x]@Wt1 + bias, fused BN stats
    k_mm<128, 128, 256, true, false, 0><<<1564, 256, 0, stream>>>(
        aggb, xb, Wt1, b1l, nullptr, nullptr, bnsums, hb, nullptr);
    // 6: GEMM relu(bn(h))@[W2l|W2r] with fused bnfin -> y2 (bf16) + z (fp32)
    k_mm<256, 0, 256, false, true, 1><<<1564, 256, 0, stream>>>(
        hb, nullptr, Wt2, nullptr, gam1, bet1, bnsums, y2b, zf);
    // 7: Layer 2 aggregate + z + bias -> out
    k_agg128<true><<<12500, 256, 0, stream>>>(y2b, rowptr, csr_src, invc, zf, b2l, nullptr, out);
}